// Round 1
// baseline (2417.297 us; speedup 1.0000x reference)
//
#include <hip/hip_runtime.h>
#include <math.h>

#define NTH 256

struct F4 { float x, y, z, w; };
__device__ __forceinline__ F4 ld4(const float* p) { return *reinterpret_cast<const F4*>(p); }
__device__ __forceinline__ void st4(float* p, F4 v) { *reinterpret_cast<F4*>(p) = v; }

__host__ __device__ constexpr int pc_(int v) { int c = 0; while (v) { c += v & 1; v >>= 1; } return c; }
__host__ __device__ constexpr int gp_sign(int a, int b) {
    int s = 0; int t = a >> 1;
    while (t) { s += pc_(t & b); t >>= 1; }
    return (s & 1) ? -1 : 1;
}

// blades order [0,1,2,4,3,5,6,7]; same table maps blade->position (involution)
#define BLADE(i) ((int)((0x76534210u >> ((i) * 4)) & 0xF))

__device__ __forceinline__ float gelu_tanh(float z) {
    float u = 0.7978845608028654f * (z + 0.044715f * z * z * z);
    return 0.5f * z * (1.0f + tanhf(u));
}

__global__ __launch_bounds__(NTH) void nbody_fused(
    const float* __restrict__ nodes, const float* __restrict__ edges,
    const float* __restrict__ src_mask,
    const float* __restrict__ W_in, const float* __restrict__ b_in,
    const float* __restrict__ W_gp, const float* __restrict__ b_gp,
    const float* __restrict__ Wq, const float* __restrict__ Wk,
    const float* __restrict__ Wv, const float* __restrict__ Wo,
    const float* __restrict__ ln1g, const float* __restrict__ ln1b,
    const float* __restrict__ ln2g, const float* __restrict__ ln2b,
    const float* __restrict__ W1, const float* __restrict__ b1,
    const float* __restrict__ W2, const float* __restrict__ b2,
    float* __restrict__ out)
{
    __shared__ __align__(16) float L[7680];
    float* XS   = L;            // [25][56] residual x
    float* HA   = L + 1400;     // h / attn-out / h2
    float* QB   = L + 2800;     // src stage, then q;  FFN: f-chunk low half
    float* KB   = L + 4200;     // mv stage, then k;   FFN: f-chunk high half
    float* VB   = L + 5600;     // gp stage, then v
    float* MK   = L + 7000;     // [25][25] mask
    float* MEAN = L + 7625;     // [25]
    float* RSTD = L + 7650;     // [25]
    float* FB   = L + 2800;     // [25][112] FFN chunk (aliases QB+KB)

    const int b = blockIdx.x;
    const int tid = threadIdx.x;

    // ---- P0: load src (25 tokens x 3 ch x 8) and mask ----
    for (int t = tid; t < 600; t += NTH) {
        int s = t / 24, r = t % 24;
        QB[t] = (s < 5) ? nodes[b * 120 + t] : edges[b * 480 + (s - 5) * 24 + r];
    }
    for (int t = tid; t < 625; t += NTH) MK[t] = src_mask[b * 625 + t];
    __syncthreads();

    // ---- P1: src_mv = mv_linear(src, W_in, b_in)  -> KB[s][n*8+i] ----
    for (int t = tid; t < 1400; t += NTH) {
        int s = t / 56, rem = t % 56, n = rem >> 3, i = rem & 7;
        int g = __popc(BLADE(i));   // grade of blade at position i
        float acc = (i == 0) ? b_in[n] : 0.0f;
        #pragma unroll
        for (int m = 0; m < 3; m++)
            acc += QB[s * 24 + m * 8 + i] * W_in[n * 12 + m * 4 + g];
        KB[t] = acc;
    }
    __syncthreads();

    // ---- P2: geometric product per (token, channel) -> VB ----
    for (int t = tid; t < 175; t += NTH) {
        int s = t / 7, n = t % 7;
        float m8[8], g8[8];
        #pragma unroll
        for (int i = 0; i < 8; i++) { m8[i] = KB[s * 56 + n * 8 + i]; g8[i] = 0.0f; }
        #pragma unroll
        for (int ai = 0; ai < 8; ai++) {
            const int a = BLADE(ai);
            #pragma unroll
            for (int bi = 0; bi < 8; bi++) {
                const int bb = BLADE(bi);
                const int j = BLADE(a ^ bb);      // position of blade a^b
                const int sg = gp_sign(a, bb);
                g8[j] += (sg > 0) ? (m8[ai] * m8[bi]) : (-m8[ai] * m8[bi]);
            }
        }
        #pragma unroll
        for (int j = 0; j < 8; j++) VB[s * 56 + n * 8 + j] = g8[j];
    }
    __syncthreads();

    // ---- P3: src2 = mv_linear(concat(mv,gp), W_gp, b_gp) -> XS ----
    for (int t = tid; t < 1400; t += NTH) {
        int s = t / 56, rem = t % 56, n = rem >> 3, i = rem & 7;
        int g = __popc(BLADE(i));
        float acc = (i == 0) ? b_gp[n] : 0.0f;
        #pragma unroll
        for (int m = 0; m < 7; m++)
            acc += KB[s * 56 + m * 8 + i] * W_gp[n * 56 + m * 4 + g];
        #pragma unroll
        for (int m = 0; m < 7; m++)
            acc += VB[s * 56 + m * 8 + i] * W_gp[n * 56 + (7 + m) * 4 + g];
        XS[t] = acc;
    }
    __syncthreads();

    const float rscale = 0.3779644730092272f;  // 1/sqrt(7)

    for (int l = 0; l < 4; l++) {
        const float* wq = Wq + l * 3136;
        const float* wk = Wk + l * 3136;
        const float* wv = Wv + l * 3136;
        const float* wo = Wo + l * 3136;
        const float* w1 = W1 + l * 12544;
        const float* w2 = W2 + l * 12544;
        const float* g1 = ln1g + l * 56; const float* e1 = ln1b + l * 56;
        const float* g2 = ln2g + l * 56; const float* e2 = ln2b + l * 56;
        const float* bb1 = b1 + l * 224; const float* bb2 = b2 + l * 56;

        // LN1 stats
        if (tid < 25) {
            float sum = 0.f, sq = 0.f;
            for (int d = 0; d < 56; d += 4) {
                F4 v = ld4(XS + tid * 56 + d);
                sum += v.x + v.y + v.z + v.w;
                sq  += v.x * v.x + v.y * v.y + v.z * v.z + v.w * v.w;
            }
            float mean = sum * (1.0f / 56.0f);
            float var  = sq  * (1.0f / 56.0f) - mean * mean;
            MEAN[tid] = mean; RSTD[tid] = rsqrtf(var + 1e-5f);
        }
        __syncthreads();
        for (int t = tid; t < 1400; t += NTH) {
            int s = t / 56, d = t % 56;
            HA[t] = (XS[t] - MEAN[s]) * RSTD[s] * g1[d] + e1[d];
        }
        __syncthreads();

        // q (scaled), k, v
        for (int o = tid; o < 350; o += NTH) {
            int s = o / 14, c = (o % 14) * 4;
            F4 acc = {0, 0, 0, 0};
            for (int k = 0; k < 56; k++) {
                float a = HA[s * 56 + k]; F4 w = ld4(wq + k * 56 + c);
                acc.x += a * w.x; acc.y += a * w.y; acc.z += a * w.z; acc.w += a * w.w;
            }
            acc.x *= rscale; acc.y *= rscale; acc.z *= rscale; acc.w *= rscale;
            st4(QB + s * 56 + c, acc);
        }
        for (int o = tid; o < 350; o += NTH) {
            int s = o / 14, c = (o % 14) * 4;
            F4 acc = {0, 0, 0, 0};
            for (int k = 0; k < 56; k++) {
                float a = HA[s * 56 + k]; F4 w = ld4(wk + k * 56 + c);
                acc.x += a * w.x; acc.y += a * w.y; acc.z += a * w.z; acc.w += a * w.w;
            }
            st4(KB + s * 56 + c, acc);
        }
        for (int o = tid; o < 350; o += NTH) {
            int s = o / 14, c = (o % 14) * 4;
            F4 acc = {0, 0, 0, 0};
            for (int k = 0; k < 56; k++) {
                float a = HA[s * 56 + k]; F4 w = ld4(wv + k * 56 + c);
                acc.x += a * w.x; acc.y += a * w.y; acc.z += a * w.z; acc.w += a * w.w;
            }
            st4(VB + s * 56 + c, acc);
        }
        __syncthreads();

        // attention: one thread per (query s, head hh); writes o into HA
        if (tid < 200) {
            int s = tid >> 3, hh = tid & 7;
            int base = hh * 7;
            float qr[7];
            #pragma unroll
            for (int d = 0; d < 7; d++) qr[d] = QB[s * 56 + base + d];
            float sc[25]; float mx = -1e30f;
            #pragma unroll
            for (int kk = 0; kk < 25; kk++) {
                float dot = 0.f;
                #pragma unroll
                for (int d = 0; d < 7; d++) dot += qr[d] * KB[kk * 56 + base + d];
                dot += MK[s * 25 + kk];
                sc[kk] = dot; mx = fmaxf(mx, dot);
            }
            float ssum = 0.f;
            #pragma unroll
            for (int kk = 0; kk < 25; kk++) { float e = __expf(sc[kk] - mx); sc[kk] = e; ssum += e; }
            float inv = 1.0f / ssum;
            float acc[7];
            #pragma unroll
            for (int d = 0; d < 7; d++) acc[d] = 0.f;
            #pragma unroll
            for (int kk = 0; kk < 25; kk++) {
                float p = sc[kk];
                #pragma unroll
                for (int d = 0; d < 7; d++) acc[d] += p * VB[kk * 56 + base + d];
            }
            #pragma unroll
            for (int d = 0; d < 7; d++) HA[s * 56 + base + d] = acc[d] * inv;
        }
        __syncthreads();

        // x += o @ Wo
        for (int o = tid; o < 350; o += NTH) {
            int s = o / 14, c = (o % 14) * 4;
            F4 acc = {0, 0, 0, 0};
            for (int k = 0; k < 56; k++) {
                float a = HA[s * 56 + k]; F4 w = ld4(wo + k * 56 + c);
                acc.x += a * w.x; acc.y += a * w.y; acc.z += a * w.z; acc.w += a * w.w;
            }
            F4 xv = ld4(XS + s * 56 + c);
            xv.x += acc.x; xv.y += acc.y; xv.z += acc.z; xv.w += acc.w;
            st4(XS + s * 56 + c, xv);
        }
        __syncthreads();

        // LN2 -> h2 in HA
        if (tid < 25) {
            float sum = 0.f, sq = 0.f;
            for (int d = 0; d < 56; d += 4) {
                F4 v = ld4(XS + tid * 56 + d);
                sum += v.x + v.y + v.z + v.w;
                sq  += v.x * v.x + v.y * v.y + v.z * v.z + v.w * v.w;
            }
            float mean = sum * (1.0f / 56.0f);
            float var  = sq  * (1.0f / 56.0f) - mean * mean;
            MEAN[tid] = mean; RSTD[tid] = rsqrtf(var + 1e-5f);
        }
        __syncthreads();
        for (int t = tid; t < 1400; t += NTH) {
            int s = t / 56, d = t % 56;
            HA[t] = (XS[t] - MEAN[s]) * RSTD[s] * g2[d] + e2[d];
        }
        __syncthreads();

        // FFN in two 112-col chunks; f-chunk aliases QB/KB
        for (int cc = 0; cc < 2; cc++) {
            for (int o = tid; o < 700; o += NTH) {
                int s = o / 28, j = (o % 28) * 4;
                int col = cc * 112 + j;
                F4 acc = {0, 0, 0, 0};
                for (int k = 0; k < 56; k++) {
                    float a = HA[s * 56 + k]; F4 w = ld4(w1 + k * 224 + col);
                    acc.x += a * w.x; acc.y += a * w.y; acc.z += a * w.z; acc.w += a * w.w;
                }
                acc.x = gelu_tanh(acc.x + bb1[col + 0]);
                acc.y = gelu_tanh(acc.y + bb1[col + 1]);
                acc.z = gelu_tanh(acc.z + bb1[col + 2]);
                acc.w = gelu_tanh(acc.w + bb1[col + 3]);
                st4(FB + s * 112 + j, acc);
            }
            __syncthreads();
            for (int o = tid; o < 350; o += NTH) {
                int s = o / 14, c = (o % 14) * 4;
                F4 acc = {0, 0, 0, 0};
                for (int j = 0; j < 112; j++) {
                    float a = FB[s * 112 + j]; F4 w = ld4(w2 + (cc * 112 + j) * 56 + c);
                    acc.x += a * w.x; acc.y += a * w.y; acc.z += a * w.z; acc.w += a * w.w;
                }
                F4 xv = ld4(XS + s * 56 + c);
                float bx = (cc == 0) ? bb2[c + 0] : 0.f;
                float by = (cc == 0) ? bb2[c + 1] : 0.f;
                float bz = (cc == 0) ? bb2[c + 2] : 0.f;
                float bw = (cc == 0) ? bb2[c + 3] : 0.f;
                xv.x += acc.x + bx; xv.y += acc.y + by; xv.z += acc.z + bz; xv.w += acc.w + bw;
                st4(XS + s * 56 + c, xv);
            }
            __syncthreads();
        }
    }

    // ---- output: x[:, :5, channel 1, :] -> (B*5, 8) ----
    for (int t = tid; t < 40; t += NTH) {
        int s = t >> 3, j = t & 7;
        out[(b * 5 + s) * 8 + j] = XS[s * 56 + 8 + j];
    }
}

extern "C" void kernel_launch(void* const* d_in, const int* in_sizes, int n_in,
                              void* d_out, int out_size, void* d_ws, size_t ws_size,
                              hipStream_t stream) {
    const float* nodes = (const float*)d_in[0];
    const float* edges = (const float*)d_in[1];
    const float* mask  = (const float*)d_in[2];
    const int B = in_sizes[0] / 120;   // (B*5, 3, 8)
    const float* W_in = (const float*)d_in[4];
    const float* b_in = (const float*)d_in[5];
    const float* W_gp = (const float*)d_in[6];
    const float* b_gp = (const float*)d_in[7];
    const float* Wq   = (const float*)d_in[8];
    const float* Wk   = (const float*)d_in[9];
    const float* Wv   = (const float*)d_in[10];
    const float* Wo   = (const float*)d_in[11];
    const float* ln1g = (const float*)d_in[12];
    const float* ln1b = (const float*)d_in[13];
    const float* ln2g = (const float*)d_in[14];
    const float* ln2b = (const float*)d_in[15];
    const float* W1   = (const float*)d_in[16];
    const float* b1   = (const float*)d_in[17];
    const float* W2   = (const float*)d_in[18];
    const float* b2   = (const float*)d_in[19];
    float* out = (float*)d_out;

    hipLaunchKernelGGL(nbody_fused, dim3(B), dim3(NTH), 0, stream,
                       nodes, edges, mask, W_in, b_in, W_gp, b_gp,
                       Wq, Wk, Wv, Wo, ln1g, ln1b, ln2g, ln2b,
                       W1, b1, W2, b2, out);
}